// Round 20
// baseline (65.975 us; speedup 1.0000x reference)
//
#include <hip/hip_runtime.h>

typedef __bf16 bf16x8 __attribute__((ext_vector_type(8)));
typedef __bf16 bf16x4 __attribute__((ext_vector_type(4)));
typedef __bf16 bf16x2 __attribute__((ext_vector_type(2)));
typedef float  f32x4  __attribute__((ext_vector_type(4)));

#define MFMA16(a, b, c) __builtin_amdgcn_mfma_f32_16x16x32_bf16((a), (b), (c), 0, 0, 0)

#define B_   4
#define NS_  128
#define GS_  8
#define DM_  512
#define MH_  8
#define DK_  64
#define L_   1024
#define NT_  4096
#define NSPLIT 4   // 4 KV tiles of 64 per block -> grid 1024 = 4 blocks/CU
#define LOG2E 1.44269504f

typedef __attribute__((address_space(1))) void as1_void;
typedef __attribute__((address_space(3))) void as3_void;

__device__ __forceinline__ void gload_lds16(const void* g, void* lds) {
  __builtin_amdgcn_global_load_lds(
      (as1_void*)(unsigned long long)g,
      (as3_void*)(unsigned int)(unsigned long long)lds, 16, 0, 0);
}

// ---------------------------------------------------------------------------
// Fused LayerNorm + weight casts + bias concat (one launch). (unchanged)
// ---------------------------------------------------------------------------
__global__ __launch_bounds__(256) void ln_cast(const float* __restrict__ X,
                                               const float* __restrict__ g,
                                               const float* __restrict__ be,
                                               __bf16* __restrict__ Xn,
                                               const float* __restrict__ Wq,
                                               const float* __restrict__ Wk,
                                               const float* __restrict__ Wv,
                                               const float* __restrict__ Wo,
                                               const float* __restrict__ bq,
                                               const float* __restrict__ bk,
                                               const float* __restrict__ bv,
                                               __bf16* __restrict__ Wcat,
                                               __bf16* __restrict__ Wob,
                                               float* __restrict__ bcat) {
  const int tid = threadIdx.x;
  if (blockIdx.x < 1024) {
    const int t  = blockIdx.x * 4 + (tid >> 6);
    const int d0 = (tid & 63) * 8;
    const long base = (long)t * DM_ + d0;
    const float4 xa = *(const float4*)(X + base);
    const float4 xb = *(const float4*)(X + base + 4);
    float s  = xa.x + xa.y + xa.z + xa.w + xb.x + xb.y + xb.z + xb.w;
    float sq = xa.x * xa.x + xa.y * xa.y + xa.z * xa.z + xa.w * xa.w
             + xb.x * xb.x + xb.y * xb.y + xb.z * xb.z + xb.w * xb.w;
#pragma unroll
    for (int off = 1; off < 64; off <<= 1) {
      s  += __shfl_xor(s, off);
      sq += __shfl_xor(sq, off);
    }
    const float mu   = s * (1.0f / DM_);
    const float var  = sq * (1.0f / DM_) - mu * mu;
    const float rstd = rsqrtf(var + 1e-5f);
    const float4 ga = *(const float4*)(g + d0);
    const float4 gb = *(const float4*)(g + d0 + 4);
    const float4 ba = *(const float4*)(be + d0);
    const float4 bb = *(const float4*)(be + d0 + 4);
    bf16x8 o;
    o[0] = (__bf16)((xa.x - mu) * rstd * ga.x + ba.x);
    o[1] = (__bf16)((xa.y - mu) * rstd * ga.y + ba.y);
    o[2] = (__bf16)((xa.z - mu) * rstd * ga.z + ba.z);
    o[3] = (__bf16)((xa.w - mu) * rstd * ga.w + ba.w);
    o[4] = (__bf16)((xb.x - mu) * rstd * gb.x + bb.x);
    o[5] = (__bf16)((xb.y - mu) * rstd * gb.y + bb.y);
    o[6] = (__bf16)((xb.z - mu) * rstd * gb.z + bb.z);
    o[7] = (__bf16)((xb.w - mu) * rstd * gb.w + bb.w);
    *(bf16x8*)(Xn + base) = o;
    return;
  }
  if (blockIdx.x == 2048) {
    for (int i = tid; i < 1536; i += 256)
      bcat[i] = (i < 512) ? bq[i] : (i < 1024 ? bk[i - 512] : bv[i - 1024]);
    return;
  }
  const int idx = (blockIdx.x - 1024) * 256 + tid;
  const int e = idx * 4;
  const int which = e >> 18;
  const int off = e & 262143;
  const float* s = (which == 0) ? Wq : (which == 1) ? Wk : (which == 2) ? Wv : Wo;
  const float4 v = *(const float4*)(s + off);
  bf16x4 o;
  o[0] = (__bf16)v.x; o[1] = (__bf16)v.y; o[2] = (__bf16)v.z; o[3] = (__bf16)v.w;
  __bf16* d = (which < 3) ? (Wcat + which * 262144 + off) : (Wob + off);
  *(bf16x4*)d = o;
}

// ---------------------------------------------------------------------------
// QKV GEMM, 2-PHASE PREFETCH (unchanged from round 16).
// ---------------------------------------------------------------------------
__global__ __launch_bounds__(256) void gemm_qkv(const __bf16* __restrict__ A,
                                                const __bf16* __restrict__ Bw,
                                                const float* __restrict__ bias,
                                                __bf16* __restrict__ Cb) {
  __shared__ __bf16 As[2][128 * 64];
  __shared__ __bf16 Bs[2][96 * 64];
  const int tid = threadIdx.x, l = tid & 63, w = tid >> 6;
  const int swz = (blockIdx.x & 7) * 64 + (blockIdx.x >> 3);  // bijective
  const int bm = swz >> 4, bn = swz & 15;
  const int wm = w >> 1, wn = w & 1;
  const int r16 = l & 15, g4 = l >> 4, kk8 = g4 * 8;
  const int srow = l >> 3, sc8 = (l & 7) * 8;

  auto STAGE = [&](int buf, int k0) {
#pragma unroll
    for (int ii = 0; ii < 4; ++ii) {
      const int i = w * 4 + ii;
      gload_lds16(A + (long)(bm * 128 + i * 8 + srow) * 512 + k0 + sc8,
                  As[buf] + i * 512);
    }
#pragma unroll
    for (int ii = 0; ii < 3; ++ii) {
      const int i = w * 3 + ii;
      gload_lds16(Bw + (long)(bn * 96 + i * 8 + srow) * 512 + k0 + sc8,
                  Bs[buf] + i * 512);
    }
  };

  STAGE(0, 0);
  __syncthreads();

  f32x4 acc[4][3] = {};
  for (int k = 0; k < 8; ++k) {
    const int cur = k & 1;
    if (k < 7) STAGE(cur ^ 1, (k + 1) * 64);   // issue BEFORE compute
    bf16x8 af[4][2];
#pragma unroll
    for (int mf = 0; mf < 4; ++mf) {
      af[mf][0] = *(const bf16x8*)(As[cur] + (wm * 64 + mf * 16 + r16) * 64 + kk8);
      af[mf][1] = *(const bf16x8*)(As[cur] + (wm * 64 + mf * 16 + r16) * 64 + 32 + kk8);
    }
    __builtin_amdgcn_s_setprio(1);
#pragma unroll
    for (int nf = 0; nf < 3; ++nf) {
      const bf16x8 b0 = *(const bf16x8*)(Bs[cur] + (wn * 48 + nf * 16 + r16) * 64 + kk8);
      const bf16x8 b1 = *(const bf16x8*)(Bs[cur] + (wn * 48 + nf * 16 + r16) * 64 + 32 + kk8);
#pragma unroll
      for (int mf = 0; mf < 4; ++mf) {
        acc[mf][nf] = MFMA16(af[mf][0], b0, acc[mf][nf]);
        acc[mf][nf] = MFMA16(af[mf][1], b1, acc[mf][nf]);
      }
    }
    __builtin_amdgcn_s_setprio(0);
    __syncthreads();
  }
#pragma unroll
  for (int mf = 0; mf < 4; ++mf) {
    const int row = bm * 128 + wm * 64 + mf * 16 + g4 * 4;
#pragma unroll
    for (int nf = 0; nf < 3; ++nf) {
      const int col = bn * 96 + wn * 48 + nf * 16 + r16;
      const float bcol = bias[col];
      const float sc = (col < 512) ? 0.125f * LOG2E : 1.0f;
#pragma unroll
      for (int r = 0; r < 4; ++r)
        Cb[(long)(row + r) * 1536 + col] = (__bf16)((acc[mf][nf][r] + bcol) * sc);
    }
  }
}

// ---------------------------------------------------------------------------
// Flash attention: round-16 structure (512 thr / 8 waves, q-block 128,
// pipelined S(t+1), defer-max, counted vmcnt) with NSPLIT=4:
// 4 KV tiles/block, grid 1024 = 4 blocks/CU (LDS trimmed to exactly 40960 B)
// -> 32 waves/CU (2x TLP vs round 19).
// ---------------------------------------------------------------------------
__global__ __launch_bounds__(512) void attn_kernel(const __bf16* __restrict__ QKV,
                                                   const int* __restrict__ sd,
                                                   const int* __restrict__ gmul,
                                                   const float* __restrict__ rho,
                                                   __bf16* __restrict__ Opart,
                                                   float2* __restrict__ ML) {
  __shared__ __align__(16) char pool[40960];
  __bf16* Ks    = (__bf16*)pool;             // 2 x 64x64 (8192 B each)
  __bf16* Vt    = (__bf16*)(pool + 16384);   // 2 x 64x72 (9216 B each)
  float*  rho_m = (float*)(pool + 34816);    // 1024 f32 (pre-scaled by log2e)
  int*    sdp   = (int*)(pool + 38912);      // 512 ints: [(i*2+par)*16 + jpair]

  const int tid = threadIdx.x;
  const int l = tid & 63;
  const int w = tid >> 6;
  const int qt = blockIdx.x & 7, sp = blockIdx.x >> 3;   // sp 0..3
  const int m = blockIdx.y, b = blockIdx.z;

  for (int p = tid; p < 1024; p += 512) rho_m[p] = rho[p * MH_ + m] * LOG2E;
  if (tid < 512) {
    const int p = tid;
    const int i = p >> 5, jl = p & 31, j = sp * 32 + jl;
    sdp[(i * 2 + (jl & 1)) * 16 + (jl >> 1)] = sd[(qt * 16 + i) * NS_ + j];
  }

  const int r16 = l & 15, g4 = l >> 4, kk8 = g4 * 8;
  const int iloc2 = (w * 2 + (r16 >> 3)) * 2 + (g4 & 1);
  int gmv[8];
#pragma unroll
  for (int hi = 0; hi < 2; ++hi)
#pragma unroll
    for (int r = 0; r < 4; ++r)
      gmv[hi * 4 + r] = gmul[(r16 & 7) * 8 + 4 * hi + r];

  const long qoff = (long)(b * L_ + qt * 128 + w * 16 + r16) * 1536 + m * 64;
  const bf16x8 aq0 = *(const bf16x8*)(QKV + qoff + kk8);
  const bf16x8 aq1 = *(const bf16x8*)(QKV + qoff + 32 + kk8);

  f32x4 acc_o[4] = {};
  float m_run = -1e30f, l_run = 0.f;

  const int srow = tid >> 3;
  const int scol = (tid & 7) * 8;
  const int krow = l >> 3;
  const int kc   = l & 7;
  const int kt0  = sp * 4;
  const int kro  = w * 8 + krow;
  const int kcs  = (kc ^ (kro & 7)) * 8;

  // prologue: K(0)->buf0, K(1)->buf1, V(0)->Vt buf0, V(1)->regs
  gload_lds16(QKV + (long)(b * L_ + kt0 * 64 + kro) * 1536 + 512 + m * 64 + kcs,
              Ks + w * 512);
  gload_lds16(QKV + (long)(b * L_ + (kt0 + 1) * 64 + kro) * 1536 + 512 + m * 64 + kcs,
              Ks + 4096 + w * 512);
  {
    const long vb0 = (long)(b * L_ + kt0 * 64 + srow) * 1536 + 1024 + m * 64;
    const bf16x8 v0 = *(const bf16x8*)(QKV + vb0 + scol);
#pragma unroll
    for (int e = 0; e < 8; ++e) {
      const int r0 = scol + e;
      Vt[r0 * 72 + (srow ^ ((((r0 >> 3) & 3)) << 4))] = v0[e];
    }
  }
  bf16x8 nv;
  {
    const long vb1 = (long)(b * L_ + (kt0 + 1) * 64 + srow) * 1536 + 1024 + m * 64;
    nv = *(const bf16x8*)(QKV + vb1 + scol);
  }
  __syncthreads();

  // S(0)
  f32x4 s4[4];
  __builtin_amdgcn_s_setprio(1);
#pragma unroll
  for (int nf = 0; nf < 4; ++nf) {
    const int tok = 32 * (nf >> 1) + 8 * (r16 >> 2) + 4 * (nf & 1) + (r16 & 3);
    const bf16x8 ak0 = *(const bf16x8*)(Ks + tok * 64 + ((g4       ^ (tok & 7)) * 8));
    const bf16x8 ak1 = *(const bf16x8*)(Ks + tok * 64 + (((4 + g4) ^ (tok & 7)) * 8));
    f32x4 a = {};
    a = MFMA16(ak0, aq0, a);
    a = MFMA16(ak1, aq1, a);
    s4[nf] = a;
  }
  __builtin_amdgcn_s_setprio(0);
  __syncthreads();   // all waves done reading Kbuf0 before t=0 restages it

#pragma unroll
  for (int t = 0; t < 4; ++t) {
    const int bb = t & 1;

    // a. write V(t+1) into Vbuf[bb^1]
    if (t < 3) {
#pragma unroll
      for (int e = 0; e < 8; ++e) {
        const int r0 = scol + e;
        Vt[(bb ^ 1) * 4608 + r0 * 72 + (srow ^ ((((r0 >> 3) & 3)) << 4))] = nv[e];
      }
    }
    // b. K(t+2) gload FIRST; c. V(t+2) load SECOND (flies across barrier)
    if (t < 2) {
      gload_lds16(QKV + (long)(b * L_ + (kt0 + t + 2) * 64 + kro) * 1536 + 512 + m * 64 + kcs,
                  Ks + bb * 4096 + w * 512);
      const long vb = (long)(b * L_ + (kt0 + t + 2) * 64 + srow) * 1536 + 1024 + m * 64;
      nv = *(const bf16x8*)(QKV + vb + scol);
    }

    // d. S(t+1) from Kbuf[bb^1]
    f32x4 s4n[4];
    if (t < 3) {
      const __bf16* Kc = Ks + (bb ^ 1) * 4096;
      __builtin_amdgcn_s_setprio(1);
#pragma unroll
      for (int nf = 0; nf < 4; ++nf) {
        const int tok = 32 * (nf >> 1) + 8 * (r16 >> 2) + 4 * (nf & 1) + (r16 & 3);
        const bf16x8 ak0 = *(const bf16x8*)(Kc + tok * 64 + ((g4       ^ (tok & 7)) * 8));
        const bf16x8 ak1 = *(const bf16x8*)(Kc + tok * 64 + (((4 + g4) ^ (tok & 7)) * 8));
        f32x4 a = {};
        a = MFMA16(ak0, aq0, a);
        a = MFMA16(ak1, aq1, a);
        s4n[nf] = a;
      }
      __builtin_amdgcn_s_setprio(0);
    }

    // e. softmax(t), defer-max (log2 units)
    const int jbase = iloc2 * 16 + t * 4 + (g4 >> 1);
    const int sv0 = sdp[jbase];
    const int sv1 = sdp[jbase + 2];
    float mx = -1e30f;
#pragma unroll
    for (int nf = 0; nf < 4; ++nf) {
      const int sv = (nf < 2) ? sv0 : sv1;
      const int hi = nf & 1;
#pragma unroll
      for (int r = 0; r < 4; ++r) {
        const float v = s4[nf][r] + rho_m[sv * 8 + gmv[hi * 4 + r]];
        s4[nf][r] = v;
        mx = fmaxf(mx, v);
      }
    }
    mx = fmaxf(mx, __shfl_xor(mx, 16));
    mx = fmaxf(mx, __shfl_xor(mx, 32));

    if (!__all(mx - m_run <= 8.0f)) {
      const float mn = fmaxf(m_run, mx);
      const float alpha = __builtin_exp2f(m_run - mn);
      m_run = mn;
      l_run *= alpha;
#pragma unroll
      for (int nf = 0; nf < 4; ++nf)
#pragma unroll
        for (int r = 0; r < 4; ++r) acc_o[nf][r] *= alpha;
    }
    float ps = 0.f;
#pragma unroll
    for (int nf = 0; nf < 4; ++nf)
#pragma unroll
      for (int r = 0; r < 4; ++r) {
        const float p = __builtin_exp2f(s4[nf][r] - m_run);
        s4[nf][r] = p;
        ps += p;
      }
    ps += __shfl_xor(ps, 16);
    ps += __shfl_xor(ps, 32);
    l_run += ps;

    // f. pack P; PV(t) on Vbuf[bb]
    bf16x8 pb0, pb1;
#pragma unroll
    for (int r = 0; r < 4; ++r) {
      pb0[r]     = (__bf16)s4[0][r];
      pb0[4 + r] = (__bf16)s4[1][r];
      pb1[r]     = (__bf16)s4[2][r];
      pb1[4 + r] = (__bf16)s4[3][r];
    }
    const __bf16* Vc = Vt + bb * 4608;
    __builtin_amdgcn_s_setprio(1);
#pragma unroll
    for (int nf = 0; nf < 4; ++nf) {
      const int d = nf * 16 + r16;
      const int msk = ((d >> 3) & 3) << 4;
      const bf16x8 av0 = *(const bf16x8*)(Vc + d * 72 + ((8 * g4) ^ msk));
      const bf16x8 av1 = *(const bf16x8*)(Vc + d * 72 + ((32 + 8 * g4) ^ msk));
      acc_o[nf] = MFMA16(av0, pb0, acc_o[nf]);
      acc_o[nf] = MFMA16(av1, pb1, acc_o[nf]);
    }
    __builtin_amdgcn_s_setprio(0);

    // g. rotate pipeline
    if (t < 3) {
#pragma unroll
      for (int nf = 0; nf < 4; ++nf) s4[nf] = s4n[nf];
    }

    // h. counted-vmcnt barrier: drain K gload; let V(t+2) load fly
    if (t < 2) {
      asm volatile("s_waitcnt vmcnt(1) lgkmcnt(0)" ::: "memory");
    } else {
      asm volatile("s_waitcnt vmcnt(0) lgkmcnt(0)" ::: "memory");
    }
    __builtin_amdgcn_s_barrier();
    __builtin_amdgcn_sched_barrier(0);
  }

  // (m,l) for split combine (log2 units)
  const int qrl = w * 16 + r16;
  const long trow = (long)b * L_ + qt * 128 + qrl;
  if (g4 == 0)
    ML[((long)sp * NT_ + trow) * MH_ + m] = float2{m_run, l_run};

  // epilogue: transpose O^T -> O via LDS (128 x 72 overlays dead K/V pool)
  __bf16* Oe = (__bf16*)pool;
  const float inv = 1.0f / l_run;
#pragma unroll
  for (int nf = 0; nf < 4; ++nf)
#pragma unroll
    for (int p2 = 0; p2 < 2; ++p2) {
      bf16x2 pr;
      pr[0] = (__bf16)(acc_o[nf][2 * p2]     * inv);
      pr[1] = (__bf16)(acc_o[nf][2 * p2 + 1] * inv);
      *(bf16x2*)(Oe + qrl * 72 + nf * 16 + 4 * g4 + 2 * p2) = pr;
    }
  __syncthreads();
  const int row = tid >> 2, c4 = tid & 3;
  const bf16x8 o0 = *(const bf16x8*)(Oe + row * 72 + c4 * 16);
  const bf16x8 o1 = *(const bf16x8*)(Oe + row * 72 + c4 * 16 + 8);
  const long obase = ((long)sp * NT_ + (long)b * L_ + qt * 128 + row) * 512 + m * 64 + c4 * 16;
  *(bf16x8*)(Opart + obase) = o0;
  *(bf16x8*)(Opart + obase + 8) = o1;
}

// ---------------------------------------------------------------------------
// Output GEMM, 2-PHASE, fused 4-partial combine (wts table in LDS).
// ---------------------------------------------------------------------------
__global__ __launch_bounds__(256) void gemm_out(const __bf16* __restrict__ Opart,
                                                const float2* __restrict__ ML,
                                                const __bf16* __restrict__ Bw,
                                                const float* __restrict__ bias,
                                                const float* __restrict__ X,
                                                float* __restrict__ Cf) {
  __shared__ __bf16 As[2][64 * 64];
  __shared__ __bf16 Bs[2][64 * 64];
  __shared__ float  wts[NSPLIT][512];   // [partial][row*8+m]
  const int tid = threadIdx.x, l = tid & 63, w = tid >> 6;
  const int bm = blockIdx.x, bn = blockIdx.y;
  const int wm = w >> 1, wn = w & 1;
  const int r16 = l & 15, g4 = l >> 4, kk8 = g4 * 8;
  const int srow = l >> 3, sc8 = (l & 7) * 8;
  const int arow = tid >> 3, achunk = (tid & 7) * 8;

  // prologue 1: combine weights for this block's 64 rows x 8 heads
  for (int pp = tid; pp < 512; pp += 256) {
    const int row = pp >> 3, mm = pp & 7;
    const long trow = (long)bm * 64 + row;
    float2 v[NSPLIT];
    float M = -1e30f;
#pragma unroll
    for (int s = 0; s < NSPLIT; ++s) {
      v[s] = ML[((long)s * NT_ + trow) * MH_ + mm];
      M = fmaxf(M, v[s].x);
    }
    float wsum = 0.f, sw[NSPLIT];
#pragma unroll
    for (int s = 0; s < NSPLIT; ++s) {
      sw[s] = v[s].y * __builtin_exp2f(v[s].x - M);
      wsum += sw[s];
    }
    const float inv = 1.0f / wsum;
#pragma unroll
    for (int s = 0; s < NSPLIT; ++s) wts[s][pp] = sw[s] * inv;
  }

  // prologue 2: load Opart(k=0) all partials, stage B(0)
  bf16x8 on[2][NSPLIT];
#pragma unroll
  for (int q = 0; q < 2; ++q) {
    const long trow = (long)bm * 64 + q * 32 + arow;
#pragma unroll
    for (int s = 0; s < NSPLIT; ++s)
      on[q][s] = *(const bf16x8*)(Opart + ((long)s * NT_ + trow) * 512 + achunk);
  }
#pragma unroll
  for (int ii = 0; ii < 2; ++ii) {
    const int i = w * 2 + ii;
    gload_lds16(Bw + (long)(bn * 64 + i * 8 + srow) * 512 + sc8, Bs[0] + i * 512);
  }
  __syncthreads();   // wts visible
#pragma unroll
  for (int q = 0; q < 2; ++q) {
    const int row = q * 32 + arow;
    float accv[8] = {};
#pragma unroll
    for (int s = 0; s < NSPLIT; ++s) {
      const float sw = wts[s][row * 8 + 0];
#pragma unroll
      for (int e = 0; e < 8; ++e) accv[e] += (float)on[q][s][e] * sw;
    }
    bf16x8 av;
#pragma unroll
    for (int e = 0; e < 8; ++e) av[e] = (__bf16)accv[e];
    *(bf16x8*)(As[0] + row * 64 + achunk) = av;
  }
  __syncthreads();   // As[0] written, Bs[0] staged (drained)

  f32x4 acc[2][2] = {};
  for (int k = 0; k < 8; ++k) {
    const int cur = k & 1;
    // issue next-step loads BEFORE compute
    if (k < 7) {
      const int kn = (k + 1) * 64;
#pragma unroll
      for (int q = 0; q < 2; ++q) {
        const long trow = (long)bm * 64 + q * 32 + arow;
#pragma unroll
        for (int s = 0; s < NSPLIT; ++s)
          on[q][s] = *(const bf16x8*)(Opart + ((long)s * NT_ + trow) * 512 + kn + achunk);
      }
#pragma unroll
      for (int ii = 0; ii < 2; ++ii) {
        const int i = w * 2 + ii;
        gload_lds16(Bw + (long)(bn * 64 + i * 8 + srow) * 512 + kn + sc8,
                    Bs[cur ^ 1] + i * 512);
      }
    }
    // MFMA on current buffers
    bf16x8 af[2][2], bf[2][2];
#pragma unroll
    for (int mf = 0; mf < 2; ++mf) {
      af[mf][0] = *(const bf16x8*)(As[cur] + (wm * 32 + mf * 16 + r16) * 64 + kk8);
      af[mf][1] = *(const bf16x8*)(As[cur] + (wm * 32 + mf * 16 + r16) * 64 + 32 + kk8);
    }
#pragma unroll
    for (int nf = 0; nf < 2; ++nf) {
      bf[nf][0] = *(const bf16x8*)(Bs[cur] + (wn * 32 + nf * 16 + r16) * 64 + kk8);
      bf[nf][1] = *(const bf16x8*)(Bs[cur] + (wn * 32 + nf * 16 + r16) * 64 + 32 + kk8);
    }
    __builtin_amdgcn_s_setprio(1);
#pragma unroll
    for (int nf = 0; nf < 2; ++nf)
#pragma unroll
      for (int mf = 0; mf < 2; ++mf) {
        acc[mf][nf] = MFMA16(af[mf][0], bf[nf][0], acc[mf][nf]);
        acc[mf][nf] = MFMA16(af[mf][1], bf[nf][1], acc[mf][nf]);
      }
    __builtin_amdgcn_s_setprio(0);
    // combine(k+1) + write AFTER compute
    if (k < 7) {
      const int mn = k + 1;
#pragma unroll
      for (int q = 0; q < 2; ++q) {
        const int row = q * 32 + arow;
        float accv[8] = {};
#pragma unroll
        for (int s = 0; s < NSPLIT; ++s) {
          const float sw = wts[s][row * 8 + mn];
#pragma unroll
          for (int e = 0; e < 8; ++e) accv[e] += (float)on[q][s][e] * sw;
        }
        bf16x8 av;
#pragma unroll
        for (int e = 0; e < 8; ++e) av[e] = (__bf16)accv[e];
        *(bf16x8*)(As[cur ^ 1] + row * 64 + achunk) = av;
      }
    }
    __syncthreads();   // one barrier per K-step
  }
#pragma unroll
  for (int mf = 0; mf < 2; ++mf) {
    const int row = bm * 64 + wm * 32 + mf * 16 + g4 * 4;
#pragma unroll
    for (int nf = 0; nf < 2; ++nf) {
      const int col = bn * 64 + wn * 32 + nf * 16 + r16;
      const float bcol = bias[col];
#pragma unroll
      for (int r = 0; r < 4; ++r)
        Cf[(long)(row + r) * 512 + col] =
            acc[mf][nf][r] + bcol + X[(long)(row + r) * 512 + col];
    }
  }
}

// ---------------------------------------------------------------------------
// launch
// ---------------------------------------------------------------------------
extern "C" void kernel_launch(void* const* d_in, const int* in_sizes, int n_in,
                              void* d_out, int out_size, void* d_ws, size_t ws_size,
                              hipStream_t stream) {
  const float* X    = (const float*)d_in[0];
  const int*   sd   = (const int*)d_in[1];
  const int*   gmul = (const int*)d_in[2];
  const float* Wq   = (const float*)d_in[3];
  const float* bq   = (const float*)d_in[4];
  const float* Wk   = (const float*)d_in[5];
  const float* bk   = (const float*)d_in[6];
  const float* Wv   = (const float*)d_in[7];
  const float* bv   = (const float*)d_in[8];
  const float* Wo   = (const float*)d_in[9];
  const float* bo   = (const float*)d_in[10];
  const float* rho  = (const float*)d_in[11];
  const float* ln_g = (const float*)d_in[12];
  const float* ln_b = (const float*)d_in[13];
  float* out = (float*)d_out;

  char* ws = (char*)d_ws;
  __bf16* Xn    = (__bf16*)(ws);                        // 4 MB
  __bf16* QKVb  = (__bf16*)(ws + (4l << 20));           // 12 MB
  __bf16* Wcat  = (__bf16*)(ws + (16l << 20));          // 1.5 MB
  __bf16* Wob   = (__bf16*)(ws + (16l << 20) + 1536 * 1024);  // 0.5 MB
  float*  bcat  = (float*)(ws + (18l << 20));           // 6 KB
  __bf16* Opart = (__bf16*)(ws + (20l << 20));          // 4 x 4 MB
  float2* ML    = (float2*)(ws + (36l << 20));          // 1 MB

  ln_cast<<<2049, 256, 0, stream>>>(X, ln_g, ln_b, Xn, Wq, Wk, Wv, Wo,
                                    bq, bk, bv, Wcat, Wob, bcat);
  gemm_qkv<<<512, 256, 0, stream>>>(Xn, Wcat, bcat, QKVb);
  attn_kernel<<<dim3(8 * NSPLIT, 8, 4), 512, 0, stream>>>(QKVb, sd, gmul, rho, Opart, ML);
  gemm_out<<<dim3(64, 8), 256, 0, stream>>>(Opart, ML, Wob, bo, X, out);
}

// Round 21
// 62.608 us; speedup vs baseline: 1.0538x; 1.0538x over previous
//
#include <hip/hip_runtime.h>

typedef __bf16 bf16x8 __attribute__((ext_vector_type(8)));
typedef __bf16 bf16x4 __attribute__((ext_vector_type(4)));
typedef __bf16 bf16x2 __attribute__((ext_vector_type(2)));
typedef float  f32x4  __attribute__((ext_vector_type(4)));

#define MFMA16(a, b, c) __builtin_amdgcn_mfma_f32_16x16x32_bf16((a), (b), (c), 0, 0, 0)

#define B_   4
#define NS_  128
#define GS_  8
#define DM_  512
#define MH_  8
#define DK_  64
#define L_   1024
#define NT_  4096
#define NSPLIT 2
#define LOG2E 1.44269504f

typedef __attribute__((address_space(1))) void as1_void;
typedef __attribute__((address_space(3))) void as3_void;

__device__ __forceinline__ void gload_lds16(const void* g, void* lds) {
  __builtin_amdgcn_global_load_lds(
      (as1_void*)(unsigned long long)g,
      (as3_void*)(unsigned int)(unsigned long long)lds, 16, 0, 0);
}

// ---------------------------------------------------------------------------
// Fused LayerNorm + weight casts + bias concat (one launch).
// ---------------------------------------------------------------------------
__global__ __launch_bounds__(256) void ln_cast(const float* __restrict__ X,
                                               const float* __restrict__ g,
                                               const float* __restrict__ be,
                                               __bf16* __restrict__ Xn,
                                               const float* __restrict__ Wq,
                                               const float* __restrict__ Wk,
                                               const float* __restrict__ Wv,
                                               const float* __restrict__ Wo,
                                               const float* __restrict__ bq,
                                               const float* __restrict__ bk,
                                               const float* __restrict__ bv,
                                               __bf16* __restrict__ Wcat,
                                               __bf16* __restrict__ Wob,
                                               float* __restrict__ bcat) {
  const int tid = threadIdx.x;
  if (blockIdx.x < 1024) {
    const int t  = blockIdx.x * 4 + (tid >> 6);
    const int d0 = (tid & 63) * 8;
    const long base = (long)t * DM_ + d0;
    const float4 xa = *(const float4*)(X + base);
    const float4 xb = *(const float4*)(X + base + 4);
    float s  = xa.x + xa.y + xa.z + xa.w + xb.x + xb.y + xb.z + xb.w;
    float sq = xa.x * xa.x + xa.y * xa.y + xa.z * xa.z + xa.w * xa.w
             + xb.x * xb.x + xb.y * xb.y + xb.z * xb.z + xb.w * xb.w;
#pragma unroll
    for (int off = 1; off < 64; off <<= 1) {
      s  += __shfl_xor(s, off);
      sq += __shfl_xor(sq, off);
    }
    const float mu   = s * (1.0f / DM_);
    const float var  = sq * (1.0f / DM_) - mu * mu;
    const float rstd = rsqrtf(var + 1e-5f);
    const float4 ga = *(const float4*)(g + d0);
    const float4 gb = *(const float4*)(g + d0 + 4);
    const float4 ba = *(const float4*)(be + d0);
    const float4 bb = *(const float4*)(be + d0 + 4);
    bf16x8 o;
    o[0] = (__bf16)((xa.x - mu) * rstd * ga.x + ba.x);
    o[1] = (__bf16)((xa.y - mu) * rstd * ga.y + ba.y);
    o[2] = (__bf16)((xa.z - mu) * rstd * ga.z + ba.z);
    o[3] = (__bf16)((xa.w - mu) * rstd * ga.w + ba.w);
    o[4] = (__bf16)((xb.x - mu) * rstd * gb.x + bb.x);
    o[5] = (__bf16)((xb.y - mu) * rstd * gb.y + bb.y);
    o[6] = (__bf16)((xb.z - mu) * rstd * gb.z + bb.z);
    o[7] = (__bf16)((xb.w - mu) * rstd * gb.w + bb.w);
    *(bf16x8*)(Xn + base) = o;
    return;
  }
  if (blockIdx.x == 2048) {
    for (int i = tid; i < 1536; i += 256)
      bcat[i] = (i < 512) ? bq[i] : (i < 1024 ? bk[i - 512] : bv[i - 1024]);
    return;
  }
  const int idx = (blockIdx.x - 1024) * 256 + tid;
  const int e = idx * 4;
  const int which = e >> 18;
  const int off = e & 262143;
  const float* s = (which == 0) ? Wq : (which == 1) ? Wk : (which == 2) ? Wv : Wo;
  const float4 v = *(const float4*)(s + off);
  bf16x4 o;
  o[0] = (__bf16)v.x; o[1] = (__bf16)v.y; o[2] = (__bf16)v.z; o[3] = (__bf16)v.w;
  __bf16* d = (which < 3) ? (Wcat + which * 262144 + off) : (Wob + off);
  *(bf16x4*)d = o;
}

// ---------------------------------------------------------------------------
// QKV GEMM, 2-PHASE PREFETCH: double-buffered LDS, STAGE(k+1) before
// compute(k), one barrier per K-step. tile 128x96, XCD swizzle.
// ---------------------------------------------------------------------------
__global__ __launch_bounds__(256) void gemm_qkv(const __bf16* __restrict__ A,
                                                const __bf16* __restrict__ Bw,
                                                const float* __restrict__ bias,
                                                __bf16* __restrict__ Cb) {
  __shared__ __bf16 As[2][128 * 64];
  __shared__ __bf16 Bs[2][96 * 64];
  const int tid = threadIdx.x, l = tid & 63, w = tid >> 6;
  const int swz = (blockIdx.x & 7) * 64 + (blockIdx.x >> 3);  // bijective
  const int bm = swz >> 4, bn = swz & 15;
  const int wm = w >> 1, wn = w & 1;
  const int r16 = l & 15, g4 = l >> 4, kk8 = g4 * 8;
  const int srow = l >> 3, sc8 = (l & 7) * 8;

  auto STAGE = [&](int buf, int k0) {
#pragma unroll
    for (int ii = 0; ii < 4; ++ii) {
      const int i = w * 4 + ii;
      gload_lds16(A + (long)(bm * 128 + i * 8 + srow) * 512 + k0 + sc8,
                  As[buf] + i * 512);
    }
#pragma unroll
    for (int ii = 0; ii < 3; ++ii) {
      const int i = w * 3 + ii;
      gload_lds16(Bw + (long)(bn * 96 + i * 8 + srow) * 512 + k0 + sc8,
                  Bs[buf] + i * 512);
    }
  };

  STAGE(0, 0);
  __syncthreads();

  f32x4 acc[4][3] = {};
  for (int k = 0; k < 8; ++k) {
    const int cur = k & 1;
    if (k < 7) STAGE(cur ^ 1, (k + 1) * 64);   // issue BEFORE compute
    bf16x8 af[4][2];
#pragma unroll
    for (int mf = 0; mf < 4; ++mf) {
      af[mf][0] = *(const bf16x8*)(As[cur] + (wm * 64 + mf * 16 + r16) * 64 + kk8);
      af[mf][1] = *(const bf16x8*)(As[cur] + (wm * 64 + mf * 16 + r16) * 64 + 32 + kk8);
    }
    __builtin_amdgcn_s_setprio(1);
#pragma unroll
    for (int nf = 0; nf < 3; ++nf) {
      const bf16x8 b0 = *(const bf16x8*)(Bs[cur] + (wn * 48 + nf * 16 + r16) * 64 + kk8);
      const bf16x8 b1 = *(const bf16x8*)(Bs[cur] + (wn * 48 + nf * 16 + r16) * 64 + 32 + kk8);
#pragma unroll
      for (int mf = 0; mf < 4; ++mf) {
        acc[mf][nf] = MFMA16(af[mf][0], b0, acc[mf][nf]);
        acc[mf][nf] = MFMA16(af[mf][1], b1, acc[mf][nf]);
      }
    }
    __builtin_amdgcn_s_setprio(0);
    __syncthreads();
  }
#pragma unroll
  for (int mf = 0; mf < 4; ++mf) {
    const int row = bm * 128 + wm * 64 + mf * 16 + g4 * 4;
#pragma unroll
    for (int nf = 0; nf < 3; ++nf) {
      const int col = bn * 96 + wn * 48 + nf * 16 + r16;
      const float bcol = bias[col];
      const float sc = (col < 512) ? 0.125f * LOG2E : 1.0f;
#pragma unroll
      for (int r = 0; r < 4; ++r)
        Cb[(long)(row + r) * 1536 + col] = (__bf16)((acc[mf][nf][r] + bcol) * sc);
    }
  }
}

// ---------------------------------------------------------------------------
// Flash attention (best measured config): 512 thr / 8 waves, q-block 128,
// NSPLIT=2, pipelined S(t+1), defer-max, counted-vmcnt barrier.
// ---------------------------------------------------------------------------
__global__ __launch_bounds__(512) void attn_kernel(const __bf16* __restrict__ QKV,
                                                   const int* __restrict__ sd,
                                                   const int* __restrict__ gmul,
                                                   const float* __restrict__ rho,
                                                   __bf16* __restrict__ Opart,
                                                   float2* __restrict__ ML) {
  __shared__ __align__(16) char pool[43008];
  __bf16* Ks    = (__bf16*)pool;             // 2 x 64x64 (8192 B each)
  __bf16* Vt    = (__bf16*)(pool + 16384);   // 2 x 64x72 (9216 B each)
  float*  rho_m = (float*)(pool + 34816);    // 1024 f32 (pre-scaled by log2e)
  int*    sdp   = (int*)(pool + 38912);      // 1024 ints

  const int tid = threadIdx.x;
  const int l = tid & 63;
  const int w = tid >> 6;
  const int qt = blockIdx.x & 7, sp = blockIdx.x >> 3;
  const int m = blockIdx.y, b = blockIdx.z;

  for (int p = tid; p < 1024; p += 512) rho_m[p] = rho[p * MH_ + m] * LOG2E;
  for (int p = tid; p < 1024; p += 512) {
    const int i = p >> 6, jl = p & 63, j = sp * 64 + jl;
    sdp[(i * 2 + (jl & 1)) * 32 + (jl >> 1)] = sd[(qt * 16 + i) * NS_ + j];
  }

  const int r16 = l & 15, g4 = l >> 4, kk8 = g4 * 8;
  const int iloc2 = (w * 2 + (r16 >> 3)) * 2 + (g4 & 1);
  int gmv[8];
#pragma unroll
  for (int hi = 0; hi < 2; ++hi)
#pragma unroll
    for (int r = 0; r < 4; ++r)
      gmv[hi * 4 + r] = gmul[(r16 & 7) * 8 + 4 * hi + r];

  const long qoff = (long)(b * L_ + qt * 128 + w * 16 + r16) * 1536 + m * 64;
  const bf16x8 aq0 = *(const bf16x8*)(QKV + qoff + kk8);
  const bf16x8 aq1 = *(const bf16x8*)(QKV + qoff + 32 + kk8);

  f32x4 acc_o[4] = {};
  float m_run = -1e30f, l_run = 0.f;

  const int srow = tid >> 3;
  const int scol = (tid & 7) * 8;
  const int krow = l >> 3;
  const int kc   = l & 7;
  const int kt0  = sp * 8;
  const int kro  = w * 8 + krow;
  const int kcs  = (kc ^ (kro & 7)) * 8;

  gload_lds16(QKV + (long)(b * L_ + kt0 * 64 + kro) * 1536 + 512 + m * 64 + kcs,
              Ks + w * 512);
  gload_lds16(QKV + (long)(b * L_ + (kt0 + 1) * 64 + kro) * 1536 + 512 + m * 64 + kcs,
              Ks + 4096 + w * 512);
  {
    const long vb0 = (long)(b * L_ + kt0 * 64 + srow) * 1536 + 1024 + m * 64;
    const bf16x8 v0 = *(const bf16x8*)(QKV + vb0 + scol);
#pragma unroll
    for (int e = 0; e < 8; ++e) {
      const int r0 = scol + e;
      Vt[r0 * 72 + (srow ^ ((((r0 >> 3) & 3)) << 4))] = v0[e];
    }
  }
  bf16x8 nv;
  {
    const long vb1 = (long)(b * L_ + (kt0 + 1) * 64 + srow) * 1536 + 1024 + m * 64;
    nv = *(const bf16x8*)(QKV + vb1 + scol);
  }
  __syncthreads();

  f32x4 s4[4];
  __builtin_amdgcn_s_setprio(1);
#pragma unroll
  for (int nf = 0; nf < 4; ++nf) {
    const int tok = 32 * (nf >> 1) + 8 * (r16 >> 2) + 4 * (nf & 1) + (r16 & 3);
    const bf16x8 ak0 = *(const bf16x8*)(Ks + tok * 64 + ((g4       ^ (tok & 7)) * 8));
    const bf16x8 ak1 = *(const bf16x8*)(Ks + tok * 64 + (((4 + g4) ^ (tok & 7)) * 8));
    f32x4 a = {};
    a = MFMA16(ak0, aq0, a);
    a = MFMA16(ak1, aq1, a);
    s4[nf] = a;
  }
  __builtin_amdgcn_s_setprio(0);
  __syncthreads();   // all waves done reading Kbuf0 (K(0)) before restage

#pragma unroll 2
  for (int t = 0; t < 8; ++t) {
    const int bb = t & 1;

    // a. write V(t+1) into Vbuf[bb^1]
    if (t < 7) {
#pragma unroll
      for (int e = 0; e < 8; ++e) {
        const int r0 = scol + e;
        Vt[(bb ^ 1) * 4608 + r0 * 72 + (srow ^ ((((r0 >> 3) & 3)) << 4))] = nv[e];
      }
    }
    // b. K(t+2) gload FIRST; c. V(t+2) load SECOND (flies across barrier)
    if (t < 6) {
      gload_lds16(QKV + (long)(b * L_ + (kt0 + t + 2) * 64 + kro) * 1536 + 512 + m * 64 + kcs,
                  Ks + bb * 4096 + w * 512);
      const long vb = (long)(b * L_ + (kt0 + t + 2) * 64 + srow) * 1536 + 1024 + m * 64;
      nv = *(const bf16x8*)(QKV + vb + scol);
    }

    // d. S(t+1) from Kbuf[bb^1]
    f32x4 s4n[4];
    if (t < 7) {
      const __bf16* Kc = Ks + (bb ^ 1) * 4096;
      __builtin_amdgcn_s_setprio(1);
#pragma unroll
      for (int nf = 0; nf < 4; ++nf) {
        const int tok = 32 * (nf >> 1) + 8 * (r16 >> 2) + 4 * (nf & 1) + (r16 & 3);
        const bf16x8 ak0 = *(const bf16x8*)(Kc + tok * 64 + ((g4       ^ (tok & 7)) * 8));
        const bf16x8 ak1 = *(const bf16x8*)(Kc + tok * 64 + (((4 + g4) ^ (tok & 7)) * 8));
        f32x4 a = {};
        a = MFMA16(ak0, aq0, a);
        a = MFMA16(ak1, aq1, a);
        s4n[nf] = a;
      }
      __builtin_amdgcn_s_setprio(0);
    }

    // e. softmax(t), defer-max (log2 units)
    const int jbase = iloc2 * 32 + t * 4 + (g4 >> 1);
    const int sv0 = sdp[jbase];
    const int sv1 = sdp[jbase + 2];
    float mx = -1e30f;
#pragma unroll
    for (int nf = 0; nf < 4; ++nf) {
      const int sv = (nf < 2) ? sv0 : sv1;
      const int hi = nf & 1;
#pragma unroll
      for (int r = 0; r < 4; ++r) {
        const float v = s4[nf][r] + rho_m[sv * 8 + gmv[hi * 4 + r]];
        s4[nf][r] = v;
        mx = fmaxf(mx, v);
      }
    }
    mx = fmaxf(mx, __shfl_xor(mx, 16));
    mx = fmaxf(mx, __shfl_xor(mx, 32));

    if (!__all(mx - m_run <= 8.0f)) {
      const float mn = fmaxf(m_run, mx);
      const float alpha = __builtin_exp2f(m_run - mn);
      m_run = mn;
      l_run *= alpha;
#pragma unroll
      for (int nf = 0; nf < 4; ++nf)
#pragma unroll
        for (int r = 0; r < 4; ++r) acc_o[nf][r] *= alpha;
    }
    float ps = 0.f;
#pragma unroll
    for (int nf = 0; nf < 4; ++nf)
#pragma unroll
      for (int r = 0; r < 4; ++r) {
        const float p = __builtin_exp2f(s4[nf][r] - m_run);
        s4[nf][r] = p;
        ps += p;
      }
    ps += __shfl_xor(ps, 16);
    ps += __shfl_xor(ps, 32);
    l_run += ps;

    // f. pack P; PV(t) on Vbuf[bb]
    bf16x8 pb0, pb1;
#pragma unroll
    for (int r = 0; r < 4; ++r) {
      pb0[r]     = (__bf16)s4[0][r];
      pb0[4 + r] = (__bf16)s4[1][r];
      pb1[r]     = (__bf16)s4[2][r];
      pb1[4 + r] = (__bf16)s4[3][r];
    }
    const __bf16* Vc = Vt + bb * 4608;
    __builtin_amdgcn_s_setprio(1);
#pragma unroll
    for (int nf = 0; nf < 4; ++nf) {
      const int d = nf * 16 + r16;
      const int msk = ((d >> 3) & 3) << 4;
      const bf16x8 av0 = *(const bf16x8*)(Vc + d * 72 + ((8 * g4) ^ msk));
      const bf16x8 av1 = *(const bf16x8*)(Vc + d * 72 + ((32 + 8 * g4) ^ msk));
      acc_o[nf] = MFMA16(av0, pb0, acc_o[nf]);
      acc_o[nf] = MFMA16(av1, pb1, acc_o[nf]);
    }
    __builtin_amdgcn_s_setprio(0);

    // g. rotate pipeline
    if (t < 7) {
#pragma unroll
      for (int nf = 0; nf < 4; ++nf) s4[nf] = s4n[nf];
    }

    // h. counted-vmcnt barrier: drain K gload; let V(t+2) load fly
    if (t < 6) {
      asm volatile("s_waitcnt vmcnt(1) lgkmcnt(0)" ::: "memory");
    } else {
      asm volatile("s_waitcnt vmcnt(0) lgkmcnt(0)" ::: "memory");
    }
    __builtin_amdgcn_s_barrier();
    __builtin_amdgcn_sched_barrier(0);
  }

  // (m,l) for split combine (log2 units)
  const int qrl = w * 16 + r16;
  const long trow = (long)b * L_ + qt * 128 + qrl;
  if (g4 == 0)
    ML[((long)sp * NT_ + trow) * MH_ + m] = float2{m_run, l_run};

  // epilogue: transpose O^T -> O via LDS (128 x 72 overlays dead K/V pool)
  __bf16* Oe = (__bf16*)pool;
  const float inv = 1.0f / l_run;
#pragma unroll
  for (int nf = 0; nf < 4; ++nf)
#pragma unroll
    for (int p2 = 0; p2 < 2; ++p2) {
      bf16x2 pr;
      pr[0] = (__bf16)(acc_o[nf][2 * p2]     * inv);
      pr[1] = (__bf16)(acc_o[nf][2 * p2 + 1] * inv);
      *(bf16x2*)(Oe + qrl * 72 + nf * 16 + 4 * g4 + 2 * p2) = pr;
    }
  __syncthreads();
  const int row = tid >> 2, c4 = tid & 3;
  const bf16x8 o0 = *(const bf16x8*)(Oe + row * 72 + c4 * 16);
  const bf16x8 o1 = *(const bf16x8*)(Oe + row * 72 + c4 * 16 + 8);
  const long obase = ((long)sp * NT_ + (long)b * L_ + qt * 128 + row) * 512 + m * 64 + c4 * 16;
  *(bf16x8*)(Opart + obase) = o0;
  *(bf16x8*)(Opart + obase + 8) = o1;
}

// ---------------------------------------------------------------------------
// Output GEMM, 2-PHASE: double-buffered LDS, one barrier per K-step,
// fused 2-partial combine with precomputed wts table (LDS).
// ---------------------------------------------------------------------------
__global__ __launch_bounds__(256) void gemm_out(const __bf16* __restrict__ Opart,
                                                const float2* __restrict__ ML,
                                                const __bf16* __restrict__ Bw,
                                                const float* __restrict__ bias,
                                                const float* __restrict__ X,
                                                float* __restrict__ Cf) {
  __shared__ __bf16 As[2][64 * 64];
  __shared__ __bf16 Bs[2][64 * 64];
  __shared__ float  wts[2][512];   // [partial][row*8+m]
  const int tid = threadIdx.x, l = tid & 63, w = tid >> 6;
  const int bm = blockIdx.x, bn = blockIdx.y;
  const int wm = w >> 1, wn = w & 1;
  const int r16 = l & 15, g4 = l >> 4, kk8 = g4 * 8;
  const int srow = l >> 3, sc8 = (l & 7) * 8;
  const int arow = tid >> 3, achunk = (tid & 7) * 8;

  for (int pp = tid; pp < 512; pp += 256) {
    const int row = pp >> 3, mm = pp & 7;
    const long trow = (long)bm * 64 + row;
    const float2 a2 = ML[trow * MH_ + mm];
    const float2 c2 = ML[((long)NT_ + trow) * MH_ + mm];
    const float M  = fmaxf(a2.x, c2.x);
    const float w0 = a2.y * __builtin_exp2f(a2.x - M);
    const float w1 = c2.y * __builtin_exp2f(c2.x - M);
    const float inv = 1.0f / (w0 + w1);
    wts[0][pp] = w0 * inv;
    wts[1][pp] = w1 * inv;
  }

  bf16x8 o0n[2], o1n[2];
#pragma unroll
  for (int q = 0; q < 2; ++q) {
    const long trow = (long)bm * 64 + q * 32 + arow;
    o0n[q] = *(const bf16x8*)(Opart + trow * 512 + achunk);
    o1n[q] = *(const bf16x8*)(Opart + ((long)NT_ + trow) * 512 + achunk);
  }
#pragma unroll
  for (int ii = 0; ii < 2; ++ii) {
    const int i = w * 2 + ii;
    gload_lds16(Bw + (long)(bn * 64 + i * 8 + srow) * 512 + sc8, Bs[0] + i * 512);
  }
  __syncthreads();
#pragma unroll
  for (int q = 0; q < 2; ++q) {
    const int row = q * 32 + arow;
    const float s0 = wts[0][row * 8 + 0];
    const float s1 = wts[1][row * 8 + 0];
    bf16x8 av;
#pragma unroll
    for (int e = 0; e < 8; ++e)
      av[e] = (__bf16)((float)o0n[q][e] * s0 + (float)o1n[q][e] * s1);
    *(bf16x8*)(As[0] + row * 64 + achunk) = av;
  }
  __syncthreads();

  f32x4 acc[2][2] = {};
  for (int k = 0; k < 8; ++k) {
    const int cur = k & 1;
    if (k < 7) {
      const int kn = (k + 1) * 64;
#pragma unroll
      for (int q = 0; q < 2; ++q) {
        const long trow = (long)bm * 64 + q * 32 + arow;
        o0n[q] = *(const bf16x8*)(Opart + trow * 512 + kn + achunk);
        o1n[q] = *(const bf16x8*)(Opart + ((long)NT_ + trow) * 512 + kn + achunk);
      }
#pragma unroll
      for (int ii = 0; ii < 2; ++ii) {
        const int i = w * 2 + ii;
        gload_lds16(Bw + (long)(bn * 64 + i * 8 + srow) * 512 + kn + sc8,
                    Bs[cur ^ 1] + i * 512);
      }
    }
    bf16x8 af[2][2], bf[2][2];
#pragma unroll
    for (int mf = 0; mf < 2; ++mf) {
      af[mf][0] = *(const bf16x8*)(As[cur] + (wm * 32 + mf * 16 + r16) * 64 + kk8);
      af[mf][1] = *(const bf16x8*)(As[cur] + (wm * 32 + mf * 16 + r16) * 64 + 32 + kk8);
    }
#pragma unroll
    for (int nf = 0; nf < 2; ++nf) {
      bf[nf][0] = *(const bf16x8*)(Bs[cur] + (wn * 32 + nf * 16 + r16) * 64 + kk8);
      bf[nf][1] = *(const bf16x8*)(Bs[cur] + (wn * 32 + nf * 16 + r16) * 64 + 32 + kk8);
    }
    __builtin_amdgcn_s_setprio(1);
#pragma unroll
    for (int nf = 0; nf < 2; ++nf)
#pragma unroll
      for (int mf = 0; mf < 2; ++mf) {
        acc[mf][nf] = MFMA16(af[mf][0], bf[nf][0], acc[mf][nf]);
        acc[mf][nf] = MFMA16(af[mf][1], bf[nf][1], acc[mf][nf]);
      }
    __builtin_amdgcn_s_setprio(0);
    if (k < 7) {
      const int mn = k + 1;
#pragma unroll
      for (int q = 0; q < 2; ++q) {
        const int row = q * 32 + arow;
        const float s0 = wts[0][row * 8 + mn];
        const float s1 = wts[1][row * 8 + mn];
        bf16x8 av;
#pragma unroll
        for (int e = 0; e < 8; ++e)
          av[e] = (__bf16)((float)o0n[q][e] * s0 + (float)o1n[q][e] * s1);
        *(bf16x8*)(As[cur ^ 1] + row * 64 + achunk) = av;
      }
    }
    __syncthreads();
  }
#pragma unroll
  for (int mf = 0; mf < 2; ++mf) {
    const int row = bm * 64 + wm * 32 + mf * 16 + g4 * 4;
#pragma unroll
    for (int nf = 0; nf < 2; ++nf) {
      const int col = bn * 64 + wn * 32 + nf * 16 + r16;
      const float bcol = bias[col];
#pragma unroll
      for (int r = 0; r < 4; ++r)
        Cf[(long)(row + r) * 512 + col] =
            acc[mf][nf][r] + bcol + X[(long)(row + r) * 512 + col];
    }
  }
}

// ---------------------------------------------------------------------------
// launch
// ---------------------------------------------------------------------------
extern "C" void kernel_launch(void* const* d_in, const int* in_sizes, int n_in,
                              void* d_out, int out_size, void* d_ws, size_t ws_size,
                              hipStream_t stream) {
  const float* X    = (const float*)d_in[0];
  const int*   sd   = (const int*)d_in[1];
  const int*   gmul = (const int*)d_in[2];
  const float* Wq   = (const float*)d_in[3];
  const float* bq   = (const float*)d_in[4];
  const float* Wk   = (const float*)d_in[5];
  const float* bk   = (const float*)d_in[6];
  const float* Wv   = (const float*)d_in[7];
  const float* bv   = (const float*)d_in[8];
  const float* Wo   = (const float*)d_in[9];
  const float* bo   = (const float*)d_in[10];
  const float* rho  = (const float*)d_in[11];
  const float* ln_g = (const float*)d_in[12];
  const float* ln_b = (const float*)d_in[13];
  float* out = (float*)d_out;

  char* ws = (char*)d_ws;
  __bf16* Xn    = (__bf16*)(ws);                        // 4 MB
  __bf16* QKVb  = (__bf16*)(ws + (4l << 20));           // 12 MB
  __bf16* Wcat  = (__bf16*)(ws + (16l << 20));          // 1.5 MB
  __bf16* Wob   = (__bf16*)(ws + (16l << 20) + 1536 * 1024);  // 0.5 MB
  float*  bcat  = (float*)(ws + (18l << 20));           // 6 KB
  __bf16* Opart = (__bf16*)(ws + (20l << 20));          // 2 x 4 MB
  float2* ML    = (float2*)(ws + (28l << 20));          // 512 KB

  ln_cast<<<2049, 256, 0, stream>>>(X, ln_g, ln_b, Xn, Wq, Wk, Wv, Wo,
                                    bq, bk, bv, Wcat, Wob, bcat);
  gemm_qkv<<<512, 256, 0, stream>>>(Xn, Wcat, bcat, QKVb);
  attn_kernel<<<dim3(8 * NSPLIT, 8, 4), 512, 0, stream>>>(QKVb, sd, gmul, rho, Opart, ML);
  gemm_out<<<dim3(64, 8), 256, 0, stream>>>(Opart, ML, Wob, bo, X, out);
}